// Round 6
// baseline (426.046 us; speedup 1.0000x reference)
//
#include <hip/hip_runtime.h>
#include <hip/hip_bf16.h>

#define CC 384
#define HW 3136            // 56*56
#define WIDTH 56
#define PLANE_ELEMS (CC*HW)  // 1204224
#define EPS 1e-5f

// bf16 x_pw for plane p lives in the 2nd half of plane p's f32 output slot:
// ushort index = p*6272 + 3136 + j   (slot = 12544 B = 6272 ushorts)
#define SLOT_U 6272
#define HALF_U 3136

typedef __attribute__((ext_vector_type(8))) short bf16x8;
typedef __attribute__((ext_vector_type(4))) float f32x4;

static __device__ __forceinline__ float bf2f(unsigned short u) {
  union { unsigned int i; float f; } x; x.i = ((unsigned int)u) << 16; return x.f;
}
static __device__ __forceinline__ unsigned short f2bf(float f) {
  union { float f; unsigned int i; } x; x.f = f;
  unsigned int r = x.i + 0x7fffu + ((x.i >> 16) & 1u);
  return (unsigned short)(r >> 16);
}
// packed f32x2 -> bf16x2 (low = a, high = b), RNE via HW pack-convert
static __device__ __forceinline__ unsigned int pkbf(float a, float b) {
  __hip_bfloat162 h = __float22bfloat162_rn(float2{a, b});
  union { __hip_bfloat162 h; unsigned int u; } c; c.h = h; return c.u;
}

// ---------------------------------------------------------------------------
// Kernel A (LDS-free): y = W @ x (1x1 conv over channels, f32 in), BN,
// + residual -> x_pw (bf16) stashed into 2nd-half slots of d_out.
// Each lane loads MFMA fragments DIRECTLY from global:
//   A[m=l15][k=q*8+t] = x[b][c0+q*8+t][j0+wv*16+l15]   (8 strided b32, L3-hot)
//   B[n=l15][k=q*8+t] = pw_w[o0+nb*16+l15][c0+q*8+t]   (2 float4, L2-hot)
// No LDS, no barriers, no transpose.
// ---------------------------------------------------------------------------
__global__ __launch_bounds__(256) void pw_gemm_bn_res(
    const float* __restrict__ xin,
    const float* __restrict__ wmat,
    const float* __restrict__ pwg, const float* __restrict__ pwb,
    const float* __restrict__ pwm, const float* __restrict__ pwv,
    unsigned short* __restrict__ xpw)   // = (ushort*)d_out
{
  const int tid = threadIdx.x;
  const int j0 = blockIdx.x * 64;   // spatial tile (3136 = 49*64)
  const int o0 = blockIdx.y * 64;   // out-channel tile (384 = 6*64)
  const int b  = blockIdx.z;
  const size_t bbase = (size_t)b * PLANE_ELEMS;

  const int lane = tid & 63;
  const int wv_  = tid >> 6;        // wave id -> spatial sub-tile
  const int l15  = lane & 15;
  const int q    = lane >> 4;

  const int jm = j0 + wv_ * 16 + l15;          // A-operand column (m) of X
  const float* xcol = xin + bbase + jm;

  f32x4 acc0 = {0.f,0.f,0.f,0.f}, acc1 = {0.f,0.f,0.f,0.f};
  f32x4 acc2 = {0.f,0.f,0.f,0.f}, acc3 = {0.f,0.f,0.f,0.f};

  for (int kt = 0; kt < 12; ++kt) {
    const int c0 = kt * 32 + q * 8;
    // A fragment: 8 strided f32 loads, pack-convert to bf16
    const float* xp = xcol + (size_t)c0 * HW;
    float a0 = xp[0];
    float a1 = xp[(size_t)1 * HW];
    float a2 = xp[(size_t)2 * HW];
    float a3 = xp[(size_t)3 * HW];
    float a4 = xp[(size_t)4 * HW];
    float a5 = xp[(size_t)5 * HW];
    float a6 = xp[(size_t)6 * HW];
    float a7 = xp[(size_t)7 * HW];
    union { bf16x8 v; unsigned int u[4]; } A;
    A.u[0] = pkbf(a0, a1); A.u[1] = pkbf(a2, a3);
    A.u[2] = pkbf(a4, a5); A.u[3] = pkbf(a6, a7);

    const float* wrow = wmat + c0 + (size_t)(o0 + l15) * CC;
    #pragma unroll
    for (int nb = 0; nb < 4; ++nb) {
      const float* wp = wrow + (size_t)(nb * 16) * CC;
      float4 w0 = *((const float4*)wp);
      float4 w1 = *((const float4*)(wp + 4));
      union { bf16x8 v; unsigned int u[4]; } B;
      B.u[0] = pkbf(w0.x, w0.y); B.u[1] = pkbf(w0.z, w0.w);
      B.u[2] = pkbf(w1.x, w1.y); B.u[3] = pkbf(w1.z, w1.w);
      if (nb == 0) acc0 = __builtin_amdgcn_mfma_f32_16x16x32_bf16(A.v, B.v, acc0, 0, 0, 0);
      if (nb == 1) acc1 = __builtin_amdgcn_mfma_f32_16x16x32_bf16(A.v, B.v, acc1, 0, 0, 0);
      if (nb == 2) acc2 = __builtin_amdgcn_mfma_f32_16x16x32_bf16(A.v, B.v, acc2, 0, 0, 0);
      if (nb == 3) acc3 = __builtin_amdgcn_mfma_f32_16x16x32_bf16(A.v, B.v, acc3, 0, 0, 0);
    }
  }

  // epilogue: x_pw = acc*scale + shift + x ; D: row m = q*4+r (=j), col n = l15 (=o)
  const int j = j0 + wv_ * 16 + q * 4;
  #pragma unroll
  for (int nb = 0; nb < 4; ++nb) {
    f32x4 acc = (nb == 0) ? acc0 : (nb == 1) ? acc1 : (nb == 2) ? acc2 : acc3;
    int o = o0 + nb * 16 + l15;
    float s = pwg[o] * rsqrtf(pwv[o] + EPS);
    float t = pwb[o] - pwm[o] * s;
    float4 xr = *((const float4*)(xin + bbase + (size_t)o * HW + j));
    ushort4 w4;
    w4.x = f2bf(acc[0] * s + t + xr.x);
    w4.y = f2bf(acc[1] * s + t + xr.y);
    w4.z = f2bf(acc[2] * s + t + xr.z);
    w4.w = f2bf(acc[3] * s + t + xr.w);
    size_t pidx = (size_t)(b * CC + o) * SLOT_U + HALF_U + j;
    *((ushort4*)(xpw + pidx)) = w4;
  }
}

// ---------------------------------------------------------------------------
// Kernel B (MFMA Toeplitz): 13x13 depthwise conv + BN_k + center-tap branch
// + exact GELU, one block per (b,c) plane.
// Tile 76 x 88 bf16, LEFT PAD 8 (Toeplitz shift 2 absorbs it) so staging is
// pure uint4: global ushort8 loads and ds_write_b128, all 16B-aligned.
// B_ky[n][k] = w[ky][k-n-2]; A reads start at col x0 (16B-aligned).
// ---------------------------------------------------------------------------
#define TSTRIDE 88
#define TROWS 76

__global__ __launch_bounds__(256) void dw_conv_mfma(
    float* __restrict__ outf,                 // d_out as f32
    const unsigned short* __restrict__ stash, // d_out as ushort (bf16 halves)
    const float* __restrict__ dwkw,
    const float* __restrict__ dkg, const float* __restrict__ dkb,
    const float* __restrict__ dkm, const float* __restrict__ dkv,
    const float* __restrict__ d1w,
    const float* __restrict__ d1g, const float* __restrict__ d1b,
    const float* __restrict__ d1m, const float* __restrict__ d1v)
{
  __shared__ __align__(16) unsigned short tile[TROWS * TSTRIDE]; // 13376 B
  __shared__ __align__(16) unsigned short Bt[13 * 16 * 32];      // 13312 B

  const int bc = blockIdx.x;
  const int c = bc % CC;
  const size_t plane_u = (size_t)bc * SLOT_U + HALF_U;  // bf16 stash base
  const size_t plane_f = (size_t)bc * HW;               // f32 out base
  const int tid = threadIdx.x;

  // stage plane: 76 rows x 11 chunks of 8 ushorts. Data: rows 6..61,
  // chunks 1..7 (cols 8..63 = gx 0..55). Everything else zero.
  for (int i = tid; i < TROWS * 11; i += 256) {
    int r = i / 11, ch = i - r * 11;
    uint4 v = {0u, 0u, 0u, 0u};
    if (r >= 6 && r < 62 && ch >= 1 && ch <= 7)
      v = *((const uint4*)(stash + plane_u + (r - 6) * WIDTH + (ch - 1) * 8));
    *((uint4*)&tile[r * TSTRIDE + ch * 8]) = v;
  }
  // Toeplitz B with shift 2: Bt[ky][n][k] = w[ky][k-n-2]
  for (int i = tid; i < 13 * 512; i += 256) {
    int ky = i >> 9, rem = i & 511, n = rem >> 5, k = rem & 31;
    int kx = k - n - 2;
    float wv = ((unsigned)kx < 13u) ? dwkw[c * 169 + ky * 13 + kx] : 0.f;
    Bt[i] = f2bf(wv);
  }

  const float sk = dkg[c] * rsqrtf(dkv[c] + EPS);
  const float tk = dkb[c] - dkm[c] * sk;
  const float s1 = d1g[c] * rsqrtf(d1v[c] + EPS);
  const float a1 = d1w[c] * s1;
  const float t1 = d1b[c] - d1m[c] * s1;
  const float tsum = tk + t1;

  __syncthreads();

  const int lane = tid & 63;
  const int l15  = lane & 15;   // A: m / D: col (x offset)
  const int q    = lane >> 4;   // A/B: k quad / D: row group
  const int wid  = tid >> 6;

  // hoist channel-constant B fragments into registers (52 VGPRs)
  bf16x8 bfr[13];
  #pragma unroll
  for (int ky = 0; ky < 13; ++ky)
    bfr[ky] = *((const bf16x8*)&Bt[(ky * 16 + l15) * 32 + q * 8]);

  // 16 tiles of 16x16 cover 64x64 >= 56x56; 4 waves -> 4 tiles each
  for (int t = wid; t < 16; t += 4) {
    const int y0 = (t >> 2) * 16, x0 = (t & 3) * 16;
    f32x4 acc = {0.f, 0.f, 0.f, 0.f};
    #pragma unroll
    for (int ky = 0; ky < 13; ++ky) {
      bf16x8 a = *((const bf16x8*)&tile[(y0 + l15 + ky) * TSTRIDE + x0 + q * 8]);
      acc = __builtin_amdgcn_mfma_f32_16x16x32_bf16(a, bfr[ky], acc, 0, 0, 0);
    }
    const int x = x0 + l15;
    if (x < WIDTH) {
      #pragma unroll
      for (int r = 0; r < 4; ++r) {
        const int y = y0 + q * 4 + r;
        if (y < WIDTH) {
          float ctr = bf2f(tile[(y + 6) * TSTRIDE + x + 8]);  // left pad 8
          float v = acc[r] * sk + tsum + ctr * a1;
          outf[plane_f + y * WIDTH + x] =
              0.5f * v * (1.f + erff(v * 0.70710678118654752f));
        }
      }
    }
  }
}

extern "C" void kernel_launch(void* const* d_in, const int* in_sizes, int n_in,
                              void* d_out, int out_size, void* d_ws, size_t ws_size,
                              hipStream_t stream) {
  const float* x     = (const float*)d_in[0];
  const float* pw_w  = (const float*)d_in[1];
  const float* pw_g  = (const float*)d_in[2];
  const float* pw_b  = (const float*)d_in[3];
  const float* pw_m  = (const float*)d_in[4];
  const float* pw_v  = (const float*)d_in[5];
  const float* dwk_w = (const float*)d_in[6];
  const float* dwk_g = (const float*)d_in[7];
  const float* dwk_b = (const float*)d_in[8];
  const float* dwk_m = (const float*)d_in[9];
  const float* dwk_v = (const float*)d_in[10];
  const float* dw1_w = (const float*)d_in[11];
  const float* dw1_g = (const float*)d_in[12];
  const float* dw1_b = (const float*)d_in[13];
  const float* dw1_m = (const float*)d_in[14];
  const float* dw1_v = (const float*)d_in[15];
  float* outf = (float*)d_out;
  unsigned short* outu = (unsigned short*)d_out;

  dim3 gridA(HW / 64, CC / 64, 16);
  pw_gemm_bn_res<<<gridA, 256, 0, stream>>>(x, pw_w, pw_g, pw_b, pw_m, pw_v, outu);

  dim3 gridB(16 * CC);
  dw_conv_mfma<<<gridB, 256, 0, stream>>>(outf, outu, dwk_w,
      dwk_g, dwk_b, dwk_m, dwk_v, dw1_w, dw1_g, dw1_b, dw1_m, dw1_v);
}